// Round 8
// baseline (1926.410 us; speedup 1.0000x reference)
//
#include <hip/hip_runtime.h>
#include <hip/hip_bf16.h>
#include <stdint.h>

#define DEVI __device__ __forceinline__

using f32x4  = __attribute__((ext_vector_type(4))) float;
using bf16x8 = __attribute__((ext_vector_type(8))) short;   // 8 bf16 in 4 VGPRs

DEVI ushort f2bf(float f) {
  union { float f; uint32_t u; } v; v.f = f;
  uint32_t u = v.u;
  uint32_t r = (u + 0x7fffu + ((u >> 16) & 1u)) >> 16;   // RNE
  return (ushort)r;
}
DEVI float bf2f(ushort h) {
  union { uint32_t u; float f; } v; v.u = ((uint32_t)h) << 16;
  return v.f;
}

// ---------------- cast fp32 -> bf16, 8 elems/thread ----------------
__global__ void k_cast_bf16(const float* __restrict__ in, ushort* __restrict__ out, int n8) {
  int i = blockIdx.x * blockDim.x + threadIdx.x;
  if (i >= n8) return;
  const float4* in4 = reinterpret_cast<const float4*>(in);
  float4 a = in4[i * 2], b = in4[i * 2 + 1];
  uint4 o;
  o.x = (uint32_t)f2bf(a.x) | ((uint32_t)f2bf(a.y) << 16);
  o.y = (uint32_t)f2bf(a.z) | ((uint32_t)f2bf(a.w) << 16);
  o.z = (uint32_t)f2bf(b.x) | ((uint32_t)f2bf(b.y) << 16);
  o.w = (uint32_t)f2bf(b.z) | ((uint32_t)f2bf(b.w) << 16);
  reinterpret_cast<uint4*>(out)[i] = o;
}

// ------------- transpose+cast: in [R][C] f32 row-major -> out [C][R] bf16 -------------
__global__ __launch_bounds__(256)
void k_transpose_cast(const float* __restrict__ in, ushort* __restrict__ out, int R, int C) {
  __shared__ float tile[64][65];
  int c0 = blockIdx.x * 64, r0 = blockIdx.y * 64;
  int t = threadIdx.x, tr = t >> 6, tc = t & 63;
#pragma unroll
  for (int i = 0; i < 16; ++i) {
    int r = i * 4 + tr;
    tile[r][tc] = in[(size_t)(r0 + r) * C + c0 + tc];
  }
  __syncthreads();
#pragma unroll
  for (int i = 0; i < 16; ++i) {
    int rr = i * 4 + tr;   // output row (= original col)
    out[(size_t)(c0 + rr) * R + r0 + tc] = f2bf(tile[tc][rr]);
  }
}

// ---------------- cos/sin tables ----------------
__global__ void k_phase(const float* __restrict__ p, float* __restrict__ c,
                        float* __restrict__ s, int n) {
  int i = blockIdx.x * blockDim.x + threadIdx.x;
  if (i < n) { float v = p[i]; c[i] = cosf(v); s[i] = sinf(v); }
}

// ---------------- concat 3 bias vectors ----------------
__global__ void k_concat3(const float* __restrict__ a, const float* __restrict__ b,
                          const float* __restrict__ c, float* __restrict__ o, int n) {
  int i = blockIdx.x * blockDim.x + threadIdx.x;
  if (i < n) { o[i] = a[i]; o[i + n] = b[i]; o[i + 2 * n] = c[i]; }
}

DEVI void glds16(const ushort* g, ushort* l) {
  __builtin_amdgcn_global_load_lds(
      (const __attribute__((address_space(1))) void*)g,
      (__attribute__((address_space(3))) void*)l, 16, 0, 0);
}

// ========== 256x256 tile GEMM, BK=32, 8 waves, 2-buf LDS (64KB -> 2 blocks/CU) ========
// C[M][N] = A[M][K] @ Bt[N][K]^T + bias.  Probe: occupancy-overlap regime (m97/m114
// mechanism): stage kt+1 at iter start, drain vmcnt(0) at iter end; the co-resident
// block fills the drain.  L2 bn-stripe mapping kept (FETCH 205->74MB, round 6).
template <typename OutT>
__global__ __launch_bounds__(512, 4)
void k_gemm256(const ushort* __restrict__ A, const ushort* __restrict__ Bt,
               const float* __restrict__ bias, OutT* __restrict__ C,
               int M, int N, int K) {
  __shared__ ushort lds[2 * 16384];   // 2 bufs x (A 16KB + B 16KB) = 64KB

  int nbx = N >> 8;
  int nwg = gridDim.x, orig = blockIdx.x;
  int bm, bn;
  if ((nbx & 7) == 0 && nbx >= 16 && (nwg & 7) == 0) {
    // XCD bn-stripe: each XCD owns nbx/8 B-panels (<=3MB, L2-resident), bn-inner
    int xcd = orig & 7, idx = orig >> 3, sw2 = nbx >> 3;
    bm = idx / sw2;
    bn = xcd * sw2 + idx % sw2;
  } else {
    int q = nwg >> 3, r8 = nwg & 7;
    int xcd = orig & 7, idx = orig >> 3;
    int swz = (xcd < r8 ? xcd * (q + 1) : r8 * (q + 1) + (xcd - r8) * q) + idx;
    bm = swz / nbx; bn = swz % nbx;
  }

  int t = threadIdx.x;
  int lane = t & 63, wid = t >> 6;
  int wm = wid >> 2, wn = wid & 3;        // 2x4 wave grid; wave tile 128x64
  int fr = lane & 15, fq = lane >> 4;
  int spR = fq ^ ((fr >> 1) & 3);         // read-side swizzled slot

  // staging source (pre-swizzled): thread t covers LDS (row rl + j*128, slot t&3)
  int rl  = t >> 2;
  int spW = (t & 3) ^ ((rl >> 1) & 3);
  const ushort* aS0 = A  + (size_t)(bm * 256 + rl) * K + spW * 8;
  const ushort* aS1 = aS0 + (size_t)128 * K;
  const ushort* bS0 = Bt + (size_t)(bn * 256 + rl) * K + spW * 8;
  const ushort* bS1 = bS0 + (size_t)128 * K;
  ushort* ldsw = lds + wid * 512;         // wave-uniform dest base (lane adds 16B)

  f32x4 acc[8][4] = {};
  int NT = K >> 5;

  // prologue: stage T0 -> buf0; drain; barrier
  glds16(aS0, ldsw);
  glds16(aS1, ldsw + 4096);
  glds16(bS0, ldsw + 8192);
  glds16(bS1, ldsw + 12288);
  asm volatile("s_waitcnt vmcnt(0)" ::: "memory");
  __builtin_amdgcn_s_barrier();
  __builtin_amdgcn_sched_barrier(0);

  int iA0 = (wm * 128 + fr) * 4 + spR;    // bf16x8 index bases into 16KB op regions
  int iB0 = (wn * 64 + fr) * 4 + spR;

  for (int kt = 0; kt < NT; ++kt) {
    // 1) issue stage of tile kt+1 into the other buffer (freed at end of kt-1)
    if (kt + 1 < NT) {
      ushort* lb = lds + ((kt + 1) & 1) * 16384 + wid * 512;
      int ko = (kt + 1) * 32;
      glds16(aS0 + ko, lb);
      glds16(aS1 + ko, lb + 4096);
      glds16(bS0 + ko, lb + 8192);
      glds16(bS1 + ko, lb + 12288);
    }
    const bf16x8* Av = reinterpret_cast<const bf16x8*>(lds + (kt & 1) * 16384);
    const bf16x8* Bv = Av + 1024;         // B region at byte 16384 (16KB / 16B)

    bf16x8 bfr[4];
#pragma unroll
    for (int nt = 0; nt < 4; ++nt) bfr[nt] = Bv[iB0 + nt * 64];

#pragma unroll
    for (int mi = 0; mi < 2; ++mi) {
      bf16x8 af[4];
#pragma unroll
      for (int m4 = 0; m4 < 4; ++m4) af[m4] = Av[iA0 + (mi * 4 + m4) * 64];
      __builtin_amdgcn_s_setprio(1);
#pragma unroll
      for (int m4 = 0; m4 < 4; ++m4)
#pragma unroll
        for (int nt = 0; nt < 4; ++nt)
          acc[mi * 4 + m4][nt] =
              __builtin_amdgcn_mfma_f32_16x16x32_bf16(af[m4], bfr[nt], acc[mi * 4 + m4][nt], 0, 0, 0);
      __builtin_amdgcn_s_setprio(0);
    }

    // 2) tile kt+1 must be fully resident before next iteration
    if (kt + 1 < NT) {
      asm volatile("s_waitcnt vmcnt(0)" ::: "memory");
      __builtin_amdgcn_s_barrier();
      __builtin_amdgcn_sched_barrier(0);
    }
  }

  // epilogue: C/D layout col = lane&15 (B-row), row-offset = fq*4+i (A-row)
#pragma unroll
  for (int mt = 0; mt < 8; ++mt)
#pragma unroll
    for (int nt = 0; nt < 4; ++nt) {
      int col = bn * 256 + wn * 64 + nt * 16 + fr;
      float bb = bias[col];
#pragma unroll
      for (int i = 0; i < 4; ++i) {
        int row = bm * 256 + wm * 128 + mt * 16 + fq * 4 + i;
        float v = acc[mt][nt][i] + bb;
        size_t off = (size_t)row * N + col;
        if constexpr (sizeof(OutT) == 2) C[off] = f2bf(v);
        else                             C[off] = v;
      }
    }
}

// ========== 256x128 tile GEMM, BK=32, 8 waves (4m x 2n), 3-buf, counted vmcnt =========
// Round-6 version (proven): LDS/buf = A 16KB + B 8KB = 24KB; x3 = 72KB -> 2 blocks/CU.
template <typename OutT>
__global__ __launch_bounds__(512, 2)
void k_gemm_n128(const ushort* __restrict__ A, const ushort* __restrict__ Bt,
                 const float* __restrict__ bias, OutT* __restrict__ C,
                 int M, int N, int K) {
  __shared__ ushort lds[3 * 12288];   // 3 bufs x 24KB = 72KB

  int nbx = N >> 7;
  int nwg = gridDim.x, orig = blockIdx.x;
  int q = nwg >> 3, r8 = nwg & 7;
  int xcd = orig & 7, idx = orig >> 3;
  int swz = (xcd < r8 ? xcd * (q + 1) : r8 * (q + 1) + (xcd - r8) * q) + idx;
  int bm = swz / nbx, bn = swz % nbx;

  int t = threadIdx.x;
  int lane = t & 63, wid = t >> 6;
  int wm = wid >> 1, wn = wid & 1;        // 4x2 wave grid; wave tile 64x64
  int fr = lane & 15, fq = lane >> 4;
  int spR = fq ^ ((fr >> 1) & 3);

  int rl  = t >> 2;
  int spW = (t & 3) ^ ((rl >> 1) & 3);
  const ushort* aS0 = A  + (size_t)(bm * 256 + rl) * K + spW * 8;
  const ushort* aS1 = aS0 + (size_t)128 * K;
  const ushort* bS0 = Bt + (size_t)(bn * 128 + rl) * K + spW * 8;
  ushort* ldsw = lds + wid * 512;

  f32x4 acc[4][4] = {};
  int NT = K >> 5;

  // prologue: stage T0 -> buf0, T1 -> buf1 (6 loads); wait T0 (T1's 3 in flight)
  glds16(aS0,      ldsw);
  glds16(aS1,      ldsw + 4096);
  glds16(bS0,      ldsw + 8192);
  glds16(aS0 + 32, ldsw + 12288);
  glds16(aS1 + 32, ldsw + 12288 + 4096);
  glds16(bS0 + 32, ldsw + 12288 + 8192);
  asm volatile("s_waitcnt vmcnt(3)" ::: "memory");
  __builtin_amdgcn_s_barrier();
  __builtin_amdgcn_sched_barrier(0);

  int iA0 = (wm * 64 + fr) * 4 + spR;     // into A region (256 rows, 16KB)
  int iB0 = (wn * 64 + fr) * 4 + spR;     // into B region (128 rows, 8KB)

  for (int kt = 0; kt < NT; ++kt) {
    if (kt + 2 < NT) {
      ushort* lb = lds + ((kt + 2) % 3) * 12288 + wid * 512;
      int ko = (kt + 2) * 32;
      glds16(aS0 + ko, lb);
      glds16(aS1 + ko, lb + 4096);
      glds16(bS0 + ko, lb + 8192);
    }
    const bf16x8* Av = reinterpret_cast<const bf16x8*>(lds + (kt % 3) * 12288);
    const bf16x8* Bv = Av + 1024;         // B region at byte 16384 (8192 ushorts)

    bf16x8 bfr[4], af[4];
#pragma unroll
    for (int nt = 0; nt < 4; ++nt) bfr[nt] = Bv[iB0 + nt * 64];
#pragma unroll
    for (int m4 = 0; m4 < 4; ++m4) af[m4] = Av[iA0 + m4 * 64];
    __builtin_amdgcn_s_setprio(1);
#pragma unroll
    for (int m4 = 0; m4 < 4; ++m4)
#pragma unroll
      for (int nt = 0; nt < 4; ++nt)
        acc[m4][nt] = __builtin_amdgcn_mfma_f32_16x16x32_bf16(af[m4], bfr[nt], acc[m4][nt], 0, 0, 0);
    __builtin_amdgcn_s_setprio(0);

    if (kt + 1 < NT) {
      if (kt + 2 < NT) { asm volatile("s_waitcnt vmcnt(3)" ::: "memory"); }
      else             { asm volatile("s_waitcnt vmcnt(0)" ::: "memory"); }
      __builtin_amdgcn_s_barrier();
      __builtin_amdgcn_sched_barrier(0);
    }
  }

#pragma unroll
  for (int m4 = 0; m4 < 4; ++m4)
#pragma unroll
    for (int nt = 0; nt < 4; ++nt) {
      int col = bn * 128 + wn * 64 + nt * 16 + fr;
      float bb = bias[col];
#pragma unroll
      for (int i = 0; i < 4; ++i) {
        int row = bm * 256 + wm * 64 + m4 * 16 + fq * 4 + i;
        float v = acc[m4][nt][i] + bb;
        size_t off = (size_t)row * N + col;
        if constexpr (sizeof(OutT) == 2) C[off] = f2bf(v);
        else                             C[off] = v;
      }
    }
}

// ---------------- per-position phase-modulated head attention (fused-QKV input) -------
// QKV row stride 12288: q at +0, k at +4096, v at +8192.  Y in [b_local,H,S,D] layout.
__global__ __launch_bounds__(256)
void k_attn(const ushort* __restrict__ QKV, const float* __restrict__ ct,
            const float* __restrict__ st, ushort* __restrict__ Y) {
  int p = blockIdx.x;
  int t = threadIdx.x;
  int lane = t & 63, wid = t >> 6;
  int d0 = t * 4;
  __shared__ float wsc[4][16];

  float q[4][4], k[4][4], v[4][4], c[4][4], s[4][4];
  const ushort* base = QKV + (size_t)p * 12288 + d0;
#pragma unroll
  for (int h = 0; h < 4; ++h) {
    ushort4 uq = *reinterpret_cast<const ushort4*>(base + h * 1024);
    ushort4 uk = *reinterpret_cast<const ushort4*>(base + 4096 + h * 1024);
    ushort4 uv = *reinterpret_cast<const ushort4*>(base + 8192 + h * 1024);
    q[h][0] = bf2f(uq.x); q[h][1] = bf2f(uq.y); q[h][2] = bf2f(uq.z); q[h][3] = bf2f(uq.w);
    k[h][0] = bf2f(uk.x); k[h][1] = bf2f(uk.y); k[h][2] = bf2f(uk.z); k[h][3] = bf2f(uk.w);
    v[h][0] = bf2f(uv.x); v[h][1] = bf2f(uv.y); v[h][2] = bf2f(uv.z); v[h][3] = bf2f(uv.w);
    float4 fc = *reinterpret_cast<const float4*>(ct + h * 1024 + d0);
    float4 fs = *reinterpret_cast<const float4*>(st + h * 1024 + d0);
    c[h][0] = fc.x; c[h][1] = fc.y; c[h][2] = fc.z; c[h][3] = fc.w;
    s[h][0] = fs.x; s[h][1] = fs.y; s[h][2] = fs.z; s[h][3] = fs.w;
  }
  float qr[4][4], qi[4][4], kr[4][4], ki[4][4];
#pragma unroll
  for (int h = 0; h < 4; ++h)
#pragma unroll
    for (int dd = 0; dd < 4; ++dd) {
      qr[h][dd] = q[h][dd] * c[h][dd];
      qi[h][dd] = q[h][dd] * s[h][dd];
      kr[h][dd] = k[h][dd] * c[h][dd];
      ki[h][dd] = k[h][dd] * s[h][dd];
    }
  float sc[16];
#pragma unroll
  for (int h = 0; h < 4; ++h)
#pragma unroll
    for (int g = 0; g < 4; ++g) {
      float a = 0.f;
#pragma unroll
      for (int dd = 0; dd < 4; ++dd)
        a += qr[h][dd] * kr[g][dd] + qi[h][dd] * ki[g][dd];
      sc[h * 4 + g] = a;
    }
#pragma unroll
  for (int j = 0; j < 16; ++j) {
    float x = sc[j];
    for (int off = 32; off; off >>= 1) x += __shfl_xor(x, off, 64);
    sc[j] = x;
  }
  if (lane == 0) {
#pragma unroll
    for (int j = 0; j < 16; ++j) wsc[wid][j] = sc[j];
  }
  __syncthreads();
  float fsc[16];
#pragma unroll
  for (int j = 0; j < 16; ++j)
    fsc[j] = (wsc[0][j] + wsc[1][j] + wsc[2][j] + wsc[3][j]) * 0.03125f;

  float attn[4][4];
#pragma unroll
  for (int h = 0; h < 4; ++h) {
    float m = fmaxf(fmaxf(fsc[h * 4 + 0], fsc[h * 4 + 1]), fmaxf(fsc[h * 4 + 2], fsc[h * 4 + 3]));
    float e0 = __expf(fsc[h * 4 + 0] - m), e1 = __expf(fsc[h * 4 + 1] - m);
    float e2 = __expf(fsc[h * 4 + 2] - m), e3 = __expf(fsc[h * 4 + 3] - m);
    float inv = 1.f / (e0 + e1 + e2 + e3);
    attn[h][0] = e0 * inv; attn[h][1] = e1 * inv; attn[h][2] = e2 * inv; attn[h][3] = e3 * inv;
  }
  int bl = p >> 11, ss = p & 2047;
#pragma unroll
  for (int h = 0; h < 4; ++h) {
    float o[4];
#pragma unroll
    for (int dd = 0; dd < 4; ++dd)
      o[dd] = attn[h][0] * v[0][dd] + attn[h][1] * v[1][dd] +
              attn[h][2] * v[2][dd] + attn[h][3] * v[3][dd];
    ushort4 ov;
    ov.x = f2bf(o[0]); ov.y = f2bf(o[1]); ov.z = f2bf(o[2]); ov.w = f2bf(o[3]);
    *reinterpret_cast<ushort4*>(Y + ((size_t)(bl * 4 + h) * 2048 + ss) * 1024 + d0) = ov;
  }
}

extern "C" void kernel_launch(void* const* d_in, const int* in_sizes, int n_in,
                              void* d_out, int out_size, void* d_ws, size_t ws_size,
                              hipStream_t stream) {
  const float* x  = (const float*)d_in[0];
  const float* ph = (const float*)d_in[1];
  const float* Wq = (const float*)d_in[2];
  const float* bq = (const float*)d_in[3];
  const float* Wk = (const float*)d_in[4];
  const float* bk = (const float*)d_in[5];
  const float* Wv = (const float*)d_in[6];
  const float* bv = (const float*)d_in[7];
  const float* Wo = (const float*)d_in[8];
  const float* bo = (const float*)d_in[9];
  float* out = (float*)d_out;

  const int B = 4, S = 2048, D = 1024, H = 4;
  const int M = B * S;          // 8192
  const int HD = H * D;         // 4096
  const int N3 = 3 * HD;        // 12288

  // ---- adaptive workspace plan (whole-b chunks only: NC in {1,2,4}) ----
  const size_t fixed = (size_t)M * D * 2          // Xb
                     + (size_t)N3 * D * 2         // WqkvT
                     + (size_t)D * HD * 2         // WoT
                     + (size_t)2 * HD * 4         // ct, st
                     + (size_t)N3 * 4;            // bqkv
  int NC; bool full_y;
  if      (ws_size >= fixed + (size_t)M     * N3 * 2 + (size_t)M * HD * 2) { NC = 1; full_y = true; }
  else if (ws_size >= fixed + (size_t)(M/2) * N3 * 2 + (size_t)M * HD * 2) { NC = 2; full_y = true; }
  else if (ws_size >= fixed + (size_t)(M/4) * N3 * 2 + (size_t)M * HD * 2) { NC = 4; full_y = true; }
  else                                                                      { NC = 4; full_y = false; }
  const int Mc = M / NC;

  char* w = (char*)d_ws;
  ushort* Xb    = (ushort*)w; w += (size_t)M * D * 2;
  ushort* WqkvT = (ushort*)w; w += (size_t)N3 * D * 2;
  ushort* WoT   = (ushort*)w; w += (size_t)D * HD * 2;
  float*  ct    = (float*)w;  w += (size_t)HD * 4;
  float*  st    = (float*)w;  w += (size_t)HD * 4;
  float*  bqkv  = (float*)w;  w += (size_t)N3 * 4;
  ushort* QKVc  = (ushort*)w; w += (size_t)Mc * N3 * 2;
  ushort* Yb    = (ushort*)w; w += (size_t)(full_y ? M : Mc) * HD * 2;

  // stage 0: casts / tables
  k_cast_bf16<<<(M * D / 8 + 255) / 256, 256, 0, stream>>>(x, Xb, M * D / 8);
  k_transpose_cast<<<dim3(HD / 64, D / 64), 256, 0, stream>>>(Wq, WqkvT,                    D, HD);
  k_transpose_cast<<<dim3(HD / 64, D / 64), 256, 0, stream>>>(Wk, WqkvT + (size_t)HD * D,   D, HD);
  k_transpose_cast<<<dim3(HD / 64, D / 64), 256, 0, stream>>>(Wv, WqkvT + (size_t)2*HD*D,   D, HD);
  k_transpose_cast<<<dim3(D / 64, HD / 64), 256, 0, stream>>>(Wo, WoT, HD, D);
  k_phase<<<(HD + 255) / 256, 256, 0, stream>>>(ph, ct, st, HD);
  k_concat3<<<(HD + 255) / 256, 256, 0, stream>>>(bq, bk, bv, bqkv, HD);

  for (int c = 0; c < NC; ++c) {
    const ushort* Ac = Xb + (size_t)c * Mc * D;
    // stage 1: fused QKV projection (bf16 out, [Mc][12288])
    k_gemm256<ushort><<<(Mc / 256) * (N3 / 256), 512, 0, stream>>>(
        Ac, WqkvT, bqkv, QKVc, Mc, N3, D);
    // stage 2: per-position head attention -> Y chunk in [b_local,H,S,D] layout
    ushort* Yc = full_y ? (Yb + (size_t)c * Mc * HD) : Yb;
    k_attn<<<Mc, 256, 0, stream>>>(QKVc, ct, st, Yc);
    if (!full_y) {
      k_gemm_n128<float><<<(Mc / 256) * (D / 128), 512, 0, stream>>>(
          Yc, WoT, bo, out + (size_t)c * Mc * D, Mc, D, HD);
    }
  }
  if (full_y) {
    // stage 3: out = view(Yb) @ Wo + bo  (fp32 out, 256x128 tile)
    k_gemm_n128<float><<<(M / 256) * (D / 128), 512, 0, stream>>>(Yb, WoT, bo, out, M, D, HD);
  }
}

// Round 9
// 390.732 us; speedup vs baseline: 4.9303x; 4.9303x over previous
//
#include <hip/hip_runtime.h>
#include <hip/hip_bf16.h>
#include <stdint.h>

#define DEVI __device__ __forceinline__

using f32x4  = __attribute__((ext_vector_type(4))) float;
using bf16x8 = __attribute__((ext_vector_type(8))) short;   // 8 bf16 in 4 VGPRs

DEVI ushort f2bf(float f) {
  union { float f; uint32_t u; } v; v.f = f;
  uint32_t u = v.u;
  uint32_t r = (u + 0x7fffu + ((u >> 16) & 1u)) >> 16;   // RNE
  return (ushort)r;
}
DEVI float bf2f(ushort h) {
  union { uint32_t u; float f; } v; v.u = ((uint32_t)h) << 16;
  return v.f;
}

// ---------------- cast fp32 -> bf16, 8 elems/thread ----------------
__global__ void k_cast_bf16(const float* __restrict__ in, ushort* __restrict__ out, int n8) {
  int i = blockIdx.x * blockDim.x + threadIdx.x;
  if (i >= n8) return;
  const float4* in4 = reinterpret_cast<const float4*>(in);
  float4 a = in4[i * 2], b = in4[i * 2 + 1];
  uint4 o;
  o.x = (uint32_t)f2bf(a.x) | ((uint32_t)f2bf(a.y) << 16);
  o.y = (uint32_t)f2bf(a.z) | ((uint32_t)f2bf(a.w) << 16);
  o.z = (uint32_t)f2bf(b.x) | ((uint32_t)f2bf(b.y) << 16);
  o.w = (uint32_t)f2bf(b.z) | ((uint32_t)f2bf(b.w) << 16);
  reinterpret_cast<uint4*>(out)[i] = o;
}

// ------------- transpose+cast fused for Wq/Wk/Wv: [1024][4096] -> [3*4096][1024] ------
__global__ __launch_bounds__(256)
void k_transpose_qkv(const float* __restrict__ w0, const float* __restrict__ w1,
                     const float* __restrict__ w2, ushort* __restrict__ out) {
  const int R = 1024, C = 4096;
  const float* in = (blockIdx.z == 0) ? w0 : (blockIdx.z == 1) ? w1 : w2;
  ushort* o = out + (size_t)blockIdx.z * C * R;
  __shared__ float tile[64][65];
  int c0 = blockIdx.x * 64, r0 = blockIdx.y * 64;
  int t = threadIdx.x, tr = t >> 6, tc = t & 63;
#pragma unroll
  for (int i = 0; i < 16; ++i) {
    int r = i * 4 + tr;
    tile[r][tc] = in[(size_t)(r0 + r) * C + c0 + tc];
  }
  __syncthreads();
#pragma unroll
  for (int i = 0; i < 16; ++i) {
    int rr = i * 4 + tr;
    o[(size_t)(c0 + rr) * R + r0 + tc] = f2bf(tile[tc][rr]);
  }
}

// ------------- transpose+cast: in [R][C] f32 row-major -> out [C][R] bf16 -------------
__global__ __launch_bounds__(256)
void k_transpose_cast(const float* __restrict__ in, ushort* __restrict__ out, int R, int C) {
  __shared__ float tile[64][65];
  int c0 = blockIdx.x * 64, r0 = blockIdx.y * 64;
  int t = threadIdx.x, tr = t >> 6, tc = t & 63;
#pragma unroll
  for (int i = 0; i < 16; ++i) {
    int r = i * 4 + tr;
    tile[r][tc] = in[(size_t)(r0 + r) * C + c0 + tc];
  }
  __syncthreads();
#pragma unroll
  for (int i = 0; i < 16; ++i) {
    int rr = i * 4 + tr;
    out[(size_t)(c0 + rr) * R + r0 + tc] = f2bf(tile[tc][rr]);
  }
}

// ---------------- cos/sin tables + fused bias concat ----------------
__global__ void k_prep(const float* __restrict__ p, const float* __restrict__ bq,
                       const float* __restrict__ bk, const float* __restrict__ bv,
                       float* __restrict__ c, float* __restrict__ s,
                       float* __restrict__ bqkv, int n) {
  int i = blockIdx.x * blockDim.x + threadIdx.x;
  if (i < n) {
    float v = p[i]; c[i] = cosf(v); s[i] = sinf(v);
    bqkv[i] = bq[i]; bqkv[i + n] = bk[i]; bqkv[i + 2 * n] = bv[i];
  }
}

DEVI void glds16(const ushort* g, ushort* l) {
  __builtin_amdgcn_global_load_lds(
      (const __attribute__((address_space(1))) void*)g,
      (__attribute__((address_space(3))) void*)l, 16, 0, 0);
}

// ========== 256x256 tile GEMM, BK=32, 8 waves, 3-buf LDS, counted vmcnt (R6-proven) ===
// C[M][N] = A[M][K] @ Bt[N][K]^T + bias.  906 TF / MfmaUtil 39% / conflicts 0 / 74MB.
template <typename OutT>
__global__ __launch_bounds__(512, 2)
void k_gemm256(const ushort* __restrict__ A, const ushort* __restrict__ Bt,
               const float* __restrict__ bias, OutT* __restrict__ C,
               int M, int N, int K) {
  __shared__ ushort lds[3 * 16384];   // 3 bufs x (A 16KB + B 16KB) = 96KB

  int nbx = N >> 8;
  int nwg = gridDim.x, orig = blockIdx.x;
  int bm, bn;
  if ((nbx & 7) == 0 && nbx >= 16 && (nwg & 7) == 0) {
    // XCD bn-stripe: each XCD owns nbx/8 B-panels (<=3MB, L2-resident), bn-inner
    int xcd = orig & 7, idx = orig >> 3, sw2 = nbx >> 3;
    bm = idx / sw2;
    bn = xcd * sw2 + idx % sw2;
  } else {
    int q = nwg >> 3, r8 = nwg & 7;
    int xcd = orig & 7, idx = orig >> 3;
    int swz = (xcd < r8 ? xcd * (q + 1) : r8 * (q + 1) + (xcd - r8) * q) + idx;
    bm = swz / nbx; bn = swz % nbx;
  }

  int t = threadIdx.x;
  int lane = t & 63, wid = t >> 6;
  int wm = wid >> 2, wn = wid & 3;        // 2x4 wave grid; wave tile 128x64
  int fr = lane & 15, fq = lane >> 4;
  int spR = fq ^ ((fr >> 1) & 3);         // read-side swizzled slot

  int rl  = t >> 2;
  int spW = (t & 3) ^ ((rl >> 1) & 3);
  const ushort* aS0 = A  + (size_t)(bm * 256 + rl) * K + spW * 8;
  const ushort* aS1 = aS0 + (size_t)128 * K;
  const ushort* bS0 = Bt + (size_t)(bn * 256 + rl) * K + spW * 8;
  const ushort* bS1 = bS0 + (size_t)128 * K;
  ushort* ldsw = lds + wid * 512;         // wave-uniform dest base (lane adds 16B)

  f32x4 acc[8][4] = {};
  int NT = K >> 5;

  // prologue: stage T0 -> buf0, T1 -> buf1 (8 loads); wait T0 (T1's 4 in flight)
  glds16(aS0,      ldsw);
  glds16(aS1,      ldsw + 4096);
  glds16(bS0,      ldsw + 8192);
  glds16(bS1,      ldsw + 12288);
  glds16(aS0 + 32, ldsw + 16384);
  glds16(aS1 + 32, ldsw + 16384 + 4096);
  glds16(bS0 + 32, ldsw + 16384 + 8192);
  glds16(bS1 + 32, ldsw + 16384 + 12288);
  asm volatile("s_waitcnt vmcnt(4)" ::: "memory");
  __builtin_amdgcn_s_barrier();
  __builtin_amdgcn_sched_barrier(0);

  int iA0 = (wm * 128 + fr) * 4 + spR;    // bf16x8 index bases into 16KB op regions
  int iB0 = (wn * 64 + fr) * 4 + spR;

  for (int kt = 0; kt < NT; ++kt) {
    // 1) issue prefetch of tile kt+2 into buffer (kt+2)%3 (freed at iter kt-1)
    if (kt + 2 < NT) {
      ushort* lb = lds + ((kt + 2) % 3) * 16384 + wid * 512;
      int ko = (kt + 2) * 32;
      glds16(aS0 + ko, lb);
      glds16(aS1 + ko, lb + 4096);
      glds16(bS0 + ko, lb + 8192);
      glds16(bS1 + ko, lb + 12288);
    }
    const bf16x8* Av = reinterpret_cast<const bf16x8*>(lds + (kt % 3) * 16384);
    const bf16x8* Bv = Av + 1024;         // B region at byte 16384 (16KB / 16B)

    bf16x8 bfr[4];
#pragma unroll
    for (int nt = 0; nt < 4; ++nt) bfr[nt] = Bv[iB0 + nt * 64];

#pragma unroll
    for (int mi = 0; mi < 2; ++mi) {
      bf16x8 af[4];
#pragma unroll
      for (int m4 = 0; m4 < 4; ++m4) af[m4] = Av[iA0 + (mi * 4 + m4) * 64];
      __builtin_amdgcn_s_setprio(1);
#pragma unroll
      for (int m4 = 0; m4 < 4; ++m4)
#pragma unroll
        for (int nt = 0; nt < 4; ++nt)
          acc[mi * 4 + m4][nt] =
              __builtin_amdgcn_mfma_f32_16x16x32_bf16(af[m4], bfr[nt], acc[mi * 4 + m4][nt], 0, 0, 0);
      __builtin_amdgcn_s_setprio(0);
    }

    // 2) make tile kt+1 ready: tile kt+2's 4 loads may stay in flight
    if (kt + 1 < NT) {
      if (kt + 2 < NT) { asm volatile("s_waitcnt vmcnt(4)" ::: "memory"); }
      else             { asm volatile("s_waitcnt vmcnt(0)" ::: "memory"); }
      __builtin_amdgcn_s_barrier();
      __builtin_amdgcn_sched_barrier(0);
    }
  }

  // epilogue: C/D layout col = lane&15 (B-row), row-offset = fq*4+i (A-row)
#pragma unroll
  for (int mt = 0; mt < 8; ++mt)
#pragma unroll
    for (int nt = 0; nt < 4; ++nt) {
      int col = bn * 256 + wn * 64 + nt * 16 + fr;
      float bb = bias[col];
#pragma unroll
      for (int i = 0; i < 4; ++i) {
        int row = bm * 256 + wm * 128 + mt * 16 + fq * 4 + i;
        float v = acc[mt][nt][i] + bb;
        size_t off = (size_t)row * N + col;
        if constexpr (sizeof(OutT) == 2) C[off] = f2bf(v);
        else                             C[off] = v;
      }
    }
}

// ========== 256x128 tile GEMM, BK=32, 8 waves (4m x 2n), 3-buf, counted vmcnt =========
// Round-6 proven (916 TF on stage 3).  LDS/buf = A 16KB + B 8KB = 24KB; x3 = 72KB.
template <typename OutT>
__global__ __launch_bounds__(512, 2)
void k_gemm_n128(const ushort* __restrict__ A, const ushort* __restrict__ Bt,
                 const float* __restrict__ bias, OutT* __restrict__ C,
                 int M, int N, int K) {
  __shared__ ushort lds[3 * 12288];   // 3 bufs x 24KB = 72KB

  int nbx = N >> 7;
  int nwg = gridDim.x, orig = blockIdx.x;
  int q = nwg >> 3, r8 = nwg & 7;
  int xcd = orig & 7, idx = orig >> 3;
  int swz = (xcd < r8 ? xcd * (q + 1) : r8 * (q + 1) + (xcd - r8) * q) + idx;
  int bm = swz / nbx, bn = swz % nbx;

  int t = threadIdx.x;
  int lane = t & 63, wid = t >> 6;
  int wm = wid >> 1, wn = wid & 1;        // 4x2 wave grid; wave tile 64x64
  int fr = lane & 15, fq = lane >> 4;
  int spR = fq ^ ((fr >> 1) & 3);

  int rl  = t >> 2;
  int spW = (t & 3) ^ ((rl >> 1) & 3);
  const ushort* aS0 = A  + (size_t)(bm * 256 + rl) * K + spW * 8;
  const ushort* aS1 = aS0 + (size_t)128 * K;
  const ushort* bS0 = Bt + (size_t)(bn * 128 + rl) * K + spW * 8;
  ushort* ldsw = lds + wid * 512;

  f32x4 acc[4][4] = {};
  int NT = K >> 5;

  glds16(aS0,      ldsw);
  glds16(aS1,      ldsw + 4096);
  glds16(bS0,      ldsw + 8192);
  glds16(aS0 + 32, ldsw + 12288);
  glds16(aS1 + 32, ldsw + 12288 + 4096);
  glds16(bS0 + 32, ldsw + 12288 + 8192);
  asm volatile("s_waitcnt vmcnt(3)" ::: "memory");
  __builtin_amdgcn_s_barrier();
  __builtin_amdgcn_sched_barrier(0);

  int iA0 = (wm * 64 + fr) * 4 + spR;     // into A region (256 rows, 16KB)
  int iB0 = (wn * 64 + fr) * 4 + spR;     // into B region (128 rows, 8KB)

  for (int kt = 0; kt < NT; ++kt) {
    if (kt + 2 < NT) {
      ushort* lb = lds + ((kt + 2) % 3) * 12288 + wid * 512;
      int ko = (kt + 2) * 32;
      glds16(aS0 + ko, lb);
      glds16(aS1 + ko, lb + 4096);
      glds16(bS0 + ko, lb + 8192);
    }
    const bf16x8* Av = reinterpret_cast<const bf16x8*>(lds + (kt % 3) * 12288);
    const bf16x8* Bv = Av + 1024;         // B region at byte 16384 (8192 ushorts)

    bf16x8 bfr[4], af[4];
#pragma unroll
    for (int nt = 0; nt < 4; ++nt) bfr[nt] = Bv[iB0 + nt * 64];
#pragma unroll
    for (int m4 = 0; m4 < 4; ++m4) af[m4] = Av[iA0 + m4 * 64];
    __builtin_amdgcn_s_setprio(1);
#pragma unroll
    for (int m4 = 0; m4 < 4; ++m4)
#pragma unroll
      for (int nt = 0; nt < 4; ++nt)
        acc[m4][nt] = __builtin_amdgcn_mfma_f32_16x16x32_bf16(af[m4], bfr[nt], acc[m4][nt], 0, 0, 0);
    __builtin_amdgcn_s_setprio(0);

    if (kt + 1 < NT) {
      if (kt + 2 < NT) { asm volatile("s_waitcnt vmcnt(3)" ::: "memory"); }
      else             { asm volatile("s_waitcnt vmcnt(0)" ::: "memory"); }
      __builtin_amdgcn_s_barrier();
      __builtin_amdgcn_sched_barrier(0);
    }
  }

#pragma unroll
  for (int m4 = 0; m4 < 4; ++m4)
#pragma unroll
    for (int nt = 0; nt < 4; ++nt) {
      int col = bn * 128 + wn * 64 + nt * 16 + fr;
      float bb = bias[col];
#pragma unroll
      for (int i = 0; i < 4; ++i) {
        int row = bm * 256 + wm * 64 + m4 * 16 + fq * 4 + i;
        float v = acc[m4][nt][i] + bb;
        size_t off = (size_t)row * N + col;
        if constexpr (sizeof(OutT) == 2) C[off] = f2bf(v);
        else                             C[off] = v;
      }
    }
}

// ---------------- per-position phase-modulated head attention (fused-QKV input) -------
// QKV row stride 12288: q at +0, k at +4096, v at +8192.  Y in [b_local,H,S,D] layout.
__global__ __launch_bounds__(256)
void k_attn(const ushort* __restrict__ QKV, const float* __restrict__ ct,
            const float* __restrict__ st, ushort* __restrict__ Y) {
  int p = blockIdx.x;
  int t = threadIdx.x;
  int lane = t & 63, wid = t >> 6;
  int d0 = t * 4;
  __shared__ float wsc[4][16];

  float q[4][4], k[4][4], v[4][4], c[4][4], s[4][4];
  const ushort* base = QKV + (size_t)p * 12288 + d0;
#pragma unroll
  for (int h = 0; h < 4; ++h) {
    ushort4 uq = *reinterpret_cast<const ushort4*>(base + h * 1024);
    ushort4 uk = *reinterpret_cast<const ushort4*>(base + 4096 + h * 1024);
    ushort4 uv = *reinterpret_cast<const ushort4*>(base + 8192 + h * 1024);
    q[h][0] = bf2f(uq.x); q[h][1] = bf2f(uq.y); q[h][2] = bf2f(uq.z); q[h][3] = bf2f(uq.w);
    k[h][0] = bf2f(uk.x); k[h][1] = bf2f(uk.y); k[h][2] = bf2f(uk.z); k[h][3] = bf2f(uk.w);
    v[h][0] = bf2f(uv.x); v[h][1] = bf2f(uv.y); v[h][2] = bf2f(uv.z); v[h][3] = bf2f(uv.w);
    float4 fc = *reinterpret_cast<const float4*>(ct + h * 1024 + d0);
    float4 fs = *reinterpret_cast<const float4*>(st + h * 1024 + d0);
    c[h][0] = fc.x; c[h][1] = fc.y; c[h][2] = fc.z; c[h][3] = fc.w;
    s[h][0] = fs.x; s[h][1] = fs.y; s[h][2] = fs.z; s[h][3] = fs.w;
  }
  float qr[4][4], qi[4][4], kr[4][4], ki[4][4];
#pragma unroll
  for (int h = 0; h < 4; ++h)
#pragma unroll
    for (int dd = 0; dd < 4; ++dd) {
      qr[h][dd] = q[h][dd] * c[h][dd];
      qi[h][dd] = q[h][dd] * s[h][dd];
      kr[h][dd] = k[h][dd] * c[h][dd];
      ki[h][dd] = k[h][dd] * s[h][dd];
    }
  float sc[16];
#pragma unroll
  for (int h = 0; h < 4; ++h)
#pragma unroll
    for (int g = 0; g < 4; ++g) {
      float a = 0.f;
#pragma unroll
      for (int dd = 0; dd < 4; ++dd)
        a += qr[h][dd] * kr[g][dd] + qi[h][dd] * ki[g][dd];
      sc[h * 4 + g] = a;
    }
#pragma unroll
  for (int j = 0; j < 16; ++j) {
    float x = sc[j];
    for (int off = 32; off; off >>= 1) x += __shfl_xor(x, off, 64);
    sc[j] = x;
  }
  if (lane == 0) {
#pragma unroll
    for (int j = 0; j < 16; ++j) wsc[wid][j] = sc[j];
  }
  __syncthreads();
  float fsc[16];
#pragma unroll
  for (int j = 0; j < 16; ++j)
    fsc[j] = (wsc[0][j] + wsc[1][j] + wsc[2][j] + wsc[3][j]) * 0.03125f;

  float attn[4][4];
#pragma unroll
  for (int h = 0; h < 4; ++h) {
    float m = fmaxf(fmaxf(fsc[h * 4 + 0], fsc[h * 4 + 1]), fmaxf(fsc[h * 4 + 2], fsc[h * 4 + 3]));
    float e0 = __expf(fsc[h * 4 + 0] - m), e1 = __expf(fsc[h * 4 + 1] - m);
    float e2 = __expf(fsc[h * 4 + 2] - m), e3 = __expf(fsc[h * 4 + 3] - m);
    float inv = 1.f / (e0 + e1 + e2 + e3);
    attn[h][0] = e0 * inv; attn[h][1] = e1 * inv; attn[h][2] = e2 * inv; attn[h][3] = e3 * inv;
  }
  int bl = p >> 11, ss = p & 2047;
#pragma unroll
  for (int h = 0; h < 4; ++h) {
    float o[4];
#pragma unroll
    for (int dd = 0; dd < 4; ++dd)
      o[dd] = attn[h][0] * v[0][dd] + attn[h][1] * v[1][dd] +
              attn[h][2] * v[2][dd] + attn[h][3] * v[3][dd];
    ushort4 ov;
    ov.x = f2bf(o[0]); ov.y = f2bf(o[1]); ov.z = f2bf(o[2]); ov.w = f2bf(o[3]);
    *reinterpret_cast<ushort4*>(Y + ((size_t)(bl * 4 + h) * 2048 + ss) * 1024 + d0) = ov;
  }
}

extern "C" void kernel_launch(void* const* d_in, const int* in_sizes, int n_in,
                              void* d_out, int out_size, void* d_ws, size_t ws_size,
                              hipStream_t stream) {
  const float* x  = (const float*)d_in[0];
  const float* ph = (const float*)d_in[1];
  const float* Wq = (const float*)d_in[2];
  const float* bq = (const float*)d_in[3];
  const float* Wk = (const float*)d_in[4];
  const float* bk = (const float*)d_in[5];
  const float* Wv = (const float*)d_in[6];
  const float* bv = (const float*)d_in[7];
  const float* Wo = (const float*)d_in[8];
  const float* bo = (const float*)d_in[9];
  float* out = (float*)d_out;

  const int B = 4, S = 2048, D = 1024, H = 4;
  const int M = B * S;          // 8192
  const int HD = H * D;         // 4096
  const int N3 = 3 * HD;        // 12288

  // ---- adaptive workspace plan (whole-b chunks only: NC in {1,2,4}) ----
  const size_t fixed = (size_t)M * D * 2          // Xb
                     + (size_t)N3 * D * 2         // WqkvT
                     + (size_t)D * HD * 2         // WoT
                     + (size_t)2 * HD * 4         // ct, st
                     + (size_t)N3 * 4;            // bqkv
  int NC; bool full_y;
  if      (ws_size >= fixed + (size_t)M     * N3 * 2 + (size_t)M * HD * 2) { NC = 1; full_y = true; }
  else if (ws_size >= fixed + (size_t)(M/2) * N3 * 2 + (size_t)M * HD * 2) { NC = 2; full_y = true; }
  else if (ws_size >= fixed + (size_t)(M/4) * N3 * 2 + (size_t)M * HD * 2) { NC = 4; full_y = true; }
  else                                                                      { NC = 4; full_y = false; }
  const int Mc = M / NC;

  char* w = (char*)d_ws;
  ushort* Xb    = (ushort*)w; w += (size_t)M * D * 2;
  ushort* WqkvT = (ushort*)w; w += (size_t)N3 * D * 2;
  ushort* WoT   = (ushort*)w; w += (size_t)D * HD * 2;
  float*  ct    = (float*)w;  w += (size_t)HD * 4;
  float*  st    = (float*)w;  w += (size_t)HD * 4;
  float*  bqkv  = (float*)w;  w += (size_t)N3 * 4;
  ushort* QKVc  = (ushort*)w; w += (size_t)Mc * N3 * 2;
  ushort* Yb    = (ushort*)w; w += (size_t)(full_y ? M : Mc) * HD * 2;

  // stage 0: casts / tables (merged: 4 launches instead of 7)
  k_cast_bf16<<<(M * D / 8 + 255) / 256, 256, 0, stream>>>(x, Xb, M * D / 8);
  k_transpose_qkv<<<dim3(HD / 64, D / 64, 3), 256, 0, stream>>>(Wq, Wk, Wv, WqkvT);
  k_transpose_cast<<<dim3(D / 64, HD / 64), 256, 0, stream>>>(Wo, WoT, HD, D);
  k_prep<<<(HD + 255) / 256, 256, 0, stream>>>(ph, bq, bk, bv, ct, st, bqkv, HD);

  for (int c = 0; c < NC; ++c) {
    const ushort* Ac = Xb + (size_t)c * Mc * D;
    // stage 1: fused QKV projection (bf16 out, [Mc][12288])
    k_gemm256<ushort><<<(Mc / 256) * (N3 / 256), 512, 0, stream>>>(
        Ac, WqkvT, bqkv, QKVc, Mc, N3, D);
    // stage 2: per-position head attention -> Y chunk in [b_local,H,S,D] layout
    ushort* Yc = full_y ? (Yb + (size_t)c * Mc * HD) : Yb;
    k_attn<<<Mc, 256, 0, stream>>>(QKVc, ct, st, Yc);
    if (!full_y) {
      k_gemm_n128<float><<<(Mc / 256) * (D / 128), 512, 0, stream>>>(
          Yc, WoT, bo, out + (size_t)c * Mc * D, Mc, D, HD);
    }
  }
  if (full_y) {
    // stage 3: out = view(Yb) @ Wo + bo  (fp32 out, 256x128 tile)
    k_gemm_n128<float><<<(M / 256) * (D / 128), 512, 0, stream>>>(Yb, WoT, bo, out, M, D, HD);
  }
}